// Round 11
// baseline (160.705 us; speedup 1.0000x reference)
//
#include <hip/hip_runtime.h>

// Fused UnifiedQCNNKernelClassifier, round 11: staged tanh (latency hiding).
// R10: 60.1us, VALUBusy 63%, VGPR 36. Issue-cost floor is ~27-37us -> the
// remaining 1.6-2x is dependency stalls: at 36 VGPRs the compiler computes a
// few dense outputs at a time with tanh inlined, so each exp2->add->rcp->fma
// chain (~30cyc trans latency) is on the critical path. Fix: stage each layer
// as (1) all G dot products -> z[], (2) all exp2 back-to-back, (3) all
// rcp+fma. Forces ~G independent trans chains in flight; VGPR should jump to
// ~80-100 (the signature that the restructure landed).

typedef float v2f __attribute__((ext_vector_type(2)));

constexpr int TPB = 256;

__device__ __forceinline__ v2f splat(float v) {
  v2f r; r.x = v; r.y = v; return r;
}
__device__ __forceinline__ v2f vfma(v2f a, v2f b, v2f c) {
  return __builtin_elementwise_fma(a, b, c);
}
__device__ __forceinline__ float fexp(float x) {            // e^x
  return __builtin_amdgcn_exp2f(x * 1.4426950408889634f);
}

template <int F, int G, bool DOTANH>
__device__ __forceinline__ void dense(const float* __restrict__ W,
                                      const float* __restrict__ b,
                                      const v2f (&in)[16], v2f (&out)[16]) {
  // Stage 1: all G pre-activations (16 independent FMA chains).
  v2f z[G];
#pragma unroll
  for (int j = 0; j < G; ++j) {
    v2f acc = splat(b[j]);
#pragma unroll
    for (int i = 0; i < F; ++i)
      acc = vfma(in[i], splat(W[j * F + i]), acc);  // w uniform -> SGPR bcast
    z[j] = acc;
  }
  if (DOTANH) {
    // Stage 2: all exp2 issued back-to-back (2G trans ops, independent).
    v2f e[G];
#pragma unroll
    for (int j = 0; j < G; ++j) {
      const v2f t = z[j] * splat(2.8853900817779268f);  // 2*log2(e)
      e[j].x = __builtin_amdgcn_exp2f(t.x);
      e[j].y = __builtin_amdgcn_exp2f(t.y);
    }
    // Stage 3: all rcp + final fma (independent across j).
#pragma unroll
    for (int j = 0; j < G; ++j) {
      const v2f d = e[j] + splat(1.0f);
      v2f r;
      r.x = __builtin_amdgcn_rcpf(d.x);
      r.y = __builtin_amdgcn_rcpf(d.y);
      out[j] = vfma(splat(-2.0f), r, splat(1.0f));
    }
  } else {
#pragma unroll
    for (int j = 0; j < G; ++j) out[j] = z[j];
  }
}

__global__ __launch_bounds__(TPB) void qcnn_fused(
    const float* __restrict__ x,
    const float* __restrict__ W1, const float* __restrict__ b1,
    const float* __restrict__ W2, const float* __restrict__ b2,
    const float* __restrict__ W3, const float* __restrict__ b3,
    const float* __restrict__ W4, const float* __restrict__ b4,
    const float* __restrict__ W5, const float* __restrict__ b5,
    const float* __restrict__ Wh, const float* __restrict__ bh,
    const float* __restrict__ Wf, const float* __restrict__ bf,
    const float* __restrict__ gammap,
    float* __restrict__ out, int n) {
  const int base = (blockIdx.x * TPB + threadIdx.x) * 2;  // contiguous pair
  const float g = gammap[0];

  v2f h0[16], hA[16], hB[16];

  // Two contiguous rows of x (8 floats each) -> 4 float4 loads, pack to v2f.
  if (base + 1 < n) {
    const float4* xp = reinterpret_cast<const float4*>(x) + (size_t)base * 2;
    float4 a0 = xp[0], a1 = xp[1];  // sample base
    float4 c0 = xp[2], c1 = xp[3];  // sample base+1
    h0[0].x = a0.x; h0[0].y = c0.x;
    h0[1].x = a0.y; h0[1].y = c0.y;
    h0[2].x = a0.z; h0[2].y = c0.z;
    h0[3].x = a0.w; h0[3].y = c0.w;
    h0[4].x = a1.x; h0[4].y = c1.x;
    h0[5].x = a1.y; h0[5].y = c1.y;
    h0[6].x = a1.z; h0[6].y = c1.z;
    h0[7].x = a1.w; h0[7].y = c1.w;
  } else if (base < n) {  // n odd tail (not hit for BATCH=2^21)
    const float4* xp = reinterpret_cast<const float4*>(x) + (size_t)base * 2;
    float4 a0 = xp[0], a1 = xp[1];
    h0[0] = splat(a0.x); h0[1] = splat(a0.y);
    h0[2] = splat(a0.z); h0[3] = splat(a0.w);
    h0[4] = splat(a1.x); h0[5] = splat(a1.y);
    h0[6] = splat(a1.z); h0[7] = splat(a1.w);
  } else {
#pragma unroll
    for (int i = 0; i < 8; ++i) h0[i] = splat(0.0f);
  }

  dense<8, 16, true>(W1, b1, h0, hA);
  dense<16, 16, true>(W2, b2, hA, hB);
  dense<16, 12, true>(W3, b3, hB, hA);
  dense<12, 8, true>(W4, b4, hA, hB);
  dense<8, 4, true>(W5, b5, hB, hA);
  dense<4, 4, false>(Wh, bh, hA, hB);  // cls_out in hB[0..3]

  const v2f c0 = hB[0], c1 = hB[1], c2 = hB[2], c3 = hB[3];
  // qnn_out == 0 -> diff = cls_out; k = exp(-g * |cls|^2)
  const v2f ss = vfma(c0, c0, vfma(c1, c1, vfma(c2, c2, c3 * c3)));
  v2f k;
  k.x = fexp(-g * ss.x);
  k.y = fexp(-g * ss.y);
  // combined = [c0..c3, 0,0,0,0, k]; Wf is [2][9] row-major
  v2f o0 = splat(bf[0]);
  o0 = vfma(splat(Wf[0]), c0, o0);
  o0 = vfma(splat(Wf[1]), c1, o0);
  o0 = vfma(splat(Wf[2]), c2, o0);
  o0 = vfma(splat(Wf[3]), c3, o0);
  o0 = vfma(splat(Wf[8]), k, o0);
  v2f o1 = splat(bf[1]);
  o1 = vfma(splat(Wf[9]),  c0, o1);
  o1 = vfma(splat(Wf[10]), c1, o1);
  o1 = vfma(splat(Wf[11]), c2, o1);
  o1 = vfma(splat(Wf[12]), c3, o1);
  o1 = vfma(splat(Wf[17]), k, o1);
  // log_softmax over 2 classes, per sample
  const v2f m = __builtin_elementwise_max(o0, o1);
  const float s0 = fexp(o0.x - m.x) + fexp(o1.x - m.x);
  const float s1 = fexp(o0.y - m.y) + fexp(o1.y - m.y);
  const float lse0 = m.x + __builtin_amdgcn_logf(s0) * 0.6931471805599453f;
  const float lse1 = m.y + __builtin_amdgcn_logf(s1) * 0.6931471805599453f;

  if (base + 1 < n) {
    float4 r;
    r.x = o0.x - lse0;
    r.y = o1.x - lse0;
    r.z = o0.y - lse1;
    r.w = o1.y - lse1;
    reinterpret_cast<float4*>(out)[base / 2] = r;
  } else if (base < n) {
    float2 r;
    r.x = o0.x - lse0;
    r.y = o1.x - lse0;
    reinterpret_cast<float2*>(out)[base] = r;
  }
}

extern "C" void kernel_launch(void* const* d_in, const int* in_sizes, int n_in,
                              void* d_out, int out_size, void* d_ws, size_t ws_size,
                              hipStream_t stream) {
  const float* x  = (const float*)d_in[0];
  const float* W1 = (const float*)d_in[1];
  const float* b1 = (const float*)d_in[2];
  const float* W2 = (const float*)d_in[3];
  const float* b2 = (const float*)d_in[4];
  const float* W3 = (const float*)d_in[5];
  const float* b3 = (const float*)d_in[6];
  const float* W4 = (const float*)d_in[7];
  const float* b4 = (const float*)d_in[8];
  const float* W5 = (const float*)d_in[9];
  const float* b5 = (const float*)d_in[10];
  const float* Wh = (const float*)d_in[11];
  const float* bh = (const float*)d_in[12];
  const float* Wf = (const float*)d_in[13];
  const float* bf = (const float*)d_in[14];
  const float* gm = (const float*)d_in[15];

  const int n = in_sizes[0] / 8;  // BATCH
  const int grid = (n + TPB * 2 - 1) / (TPB * 2);
  qcnn_fused<<<grid, TPB, 0, stream>>>(x, W1, b1, W2, b2, W3, b3, W4, b4,
                                       W5, b5, Wh, bh, Wf, bf, gm,
                                       (float*)d_out, n);
}